// Round 1
// baseline (2297.441 us; speedup 1.0000x reference)
//
#include <hip/hip_runtime.h>
#include <cstddef>
#include <cstdint>

#define B_   2
#define L_   2048
#define C_   768
#define DI   1536   // D_INNER
#define DS   16     // D_STATE
#define DC   4      // D_CONV
#define DTR  48     // DT_RANK
#define E2   3072   // 2*D_INNER
#define NXP  80     // DT_RANK + 2*DS
#define NCH  128    // scan chunks
#define LCH  16     // L per chunk (NCH*LCH == L_)
#define ML   (B_*L_)  // 4096 rows

// ---------------- mean over H*W = 64 ----------------
// one float4 per thread; 16 threads = one (b,l,c) group
__global__ __launch_bounds__(256) void k_reduce(const float4* __restrict__ x,
                                                float* __restrict__ xc) {
  int gid = blockIdx.x * 256 + threadIdx.x;
  float4 v = x[gid];
  float s = (v.x + v.y) + (v.z + v.w);
  s += __shfl_xor(s, 1, 16);
  s += __shfl_xor(s, 2, 16);
  s += __shfl_xor(s, 4, 16);
  s += __shfl_xor(s, 8, 16);
  if ((threadIdx.x & 15) == 0) xc[gid >> 4] = s * (1.0f / 64.0f);
}

// ---------------- generic fp32 GEMM: C = A(MxK) * B(NxK)^T ----------------
// MODE 0: plain store. MODE 1: softplus(acc + bias[n]).
template <int BM, int BN, int TM, int TN, int MODE>
__global__ __launch_bounds__(256) void k_gemm(const float* __restrict__ A, int lda,
                                              const float* __restrict__ Bm, int ldb,
                                              float* __restrict__ Cm, int ldc,
                                              int M, int N, int K,
                                              const float* __restrict__ bias) {
  constexpr int BK = 16;
  __shared__ float As[BK][BM + 4];   // [k][m], +4 keeps rows 16B-aligned
  __shared__ float Bs[BK][BN + 4];
  const int tid = threadIdx.x;
  const int tx = tid & 15;
  const int ty = tid >> 4;
  const int m0 = blockIdx.x * BM;
  const int n0 = blockIdx.y * BN;

  float acc[TM][TN];
#pragma unroll
  for (int i = 0; i < TM; ++i)
#pragma unroll
    for (int j = 0; j < TN; ++j) acc[i][j] = 0.f;

  for (int k0 = 0; k0 < K; k0 += BK) {
#pragma unroll
    for (int t = 0; t < BM / 16; ++t) {
      int e = t * 256 + tid;
      int row = e >> 4, col = e & 15;
      int gm = m0 + row, gk = k0 + col;
      As[col][row] = (gm < M && gk < K) ? A[(size_t)gm * lda + gk] : 0.f;
    }
#pragma unroll
    for (int t = 0; t < BN / 16; ++t) {
      int e = t * 256 + tid;
      int row = e >> 4, col = e & 15;
      int gn = n0 + row, gk = k0 + col;
      Bs[col][row] = (gn < N && gk < K) ? Bm[(size_t)gn * ldb + gk] : 0.f;
    }
    __syncthreads();
#pragma unroll
    for (int kk = 0; kk < BK; ++kk) {
      float a[TM], bv[TN];
#pragma unroll
      for (int i = 0; i < TM; ++i) a[i] = As[kk][ty * TM + i];
#pragma unroll
      for (int j = 0; j < TN; ++j) bv[j] = Bs[kk][tx * TN + j];
#pragma unroll
      for (int i = 0; i < TM; ++i)
#pragma unroll
        for (int j = 0; j < TN; ++j) acc[i][j] = fmaf(a[i], bv[j], acc[i][j]);
    }
    __syncthreads();
  }
#pragma unroll
  for (int i = 0; i < TM; ++i) {
    int gm = m0 + ty * TM + i;
    if (gm >= M) continue;
#pragma unroll
    for (int j = 0; j < TN; ++j) {
      int gn = n0 + tx * TN + j;
      if (gn >= N) continue;
      float v = acc[i][j];
      if (MODE == 1) {
        v += bias[gn];
        v = fmaxf(v, 0.f) + log1pf(expf(-fabsf(v)));  // stable softplus
      }
      Cm[(size_t)gm * ldc + gn] = v;
    }
  }
}

// ---------------- causal depthwise conv (4 taps) + SiLU ----------------
__global__ __launch_bounds__(256) void k_conv(const float* __restrict__ xz,
                                              const float* __restrict__ cw,
                                              const float* __restrict__ cb,
                                              float* __restrict__ xh) {
  int gid = blockIdx.x * 256 + threadIdx.x;  // over B*L*DI, d fastest
  int d = gid % DI;
  int bl = gid / DI;
  int l = bl % L_;
  const float* base = xz + (size_t)(bl - l) * E2 + d;  // start of this batch's rows
  float acc = cb[d];
#pragma unroll
  for (int k = 0; k < DC; ++k) {
    int ll = l + k - (DC - 1);
    float xv = (ll >= 0) ? base[(size_t)ll * E2] : 0.f;
    acc = fmaf(xv, cw[d * DC + k], acc);
  }
  float sig = 1.f / (1.f + expf(-acc));
  xh[gid] = acc * sig;
}

// ---------------- scan pass1: per-chunk local scan ----------------
// block = 256 d's for one (b, chunk). Stores local h_end and sum(delta).
__global__ __launch_bounds__(256) void k_scan1(const float* __restrict__ delta,
                                               const float* __restrict__ xh,
                                               const float* __restrict__ xdb,
                                               const float* __restrict__ A_log,
                                               float* __restrict__ hend,
                                               float* __restrict__ sd) {
  int tid = threadIdx.x;
  int bid = blockIdx.x;
  int dblk = bid % (DI / 256);
  int c = (bid / (DI / 256)) % NCH;
  int b = bid / ((DI / 256) * NCH);
  int d = dblk * 256 + tid;

  float a[DS];
#pragma unroll
  for (int s = 0; s < DS; ++s) a[s] = -expf(A_log[d * DS + s]);
  float h[DS];
#pragma unroll
  for (int s = 0; s < DS; ++s) h[s] = 0.f;
  float sum_delta = 0.f;

  int l0 = c * LCH;
  for (int i = 0; i < LCH; ++i) {
    size_t bl = (size_t)b * L_ + (l0 + i);
    float dt = delta[bl * DI + d];
    float xv = xh[bl * DI + d];
    sum_delta += dt;
    float u = dt * xv;
    const float* Brow = xdb + bl * NXP + DTR;  // Bs view
#pragma unroll
    for (int s = 0; s < DS; ++s) {
      float dA = expf(dt * a[s]);
      h[s] = fmaf(dA, h[s], u * Brow[s]);
    }
  }
  size_t base = (size_t)(b * NCH + c) * DS * DI;
#pragma unroll
  for (int s = 0; s < DS; ++s) hend[base + (size_t)s * DI + d] = h[s];
  sd[(size_t)(b * NCH + c) * DI + d] = sum_delta;
}

// ---------------- scan pass2: cross-chunk carry ----------------
// one thread per (b, s, d); writes h_init for every chunk
__global__ __launch_bounds__(256) void k_scan2(const float* __restrict__ A_log,
                                               const float* __restrict__ sd,
                                               const float* __restrict__ hend,
                                               float* __restrict__ hinit) {
  int gid = blockIdx.x * 256 + threadIdx.x;  // B*DS*DI = 49152
  int d = gid % DI;
  int s = (gid / DI) % DS;
  int b = gid / (DI * DS);
  float a = -expf(A_log[d * DS + s]);
  float h = 0.f;
  for (int c = 0; c < NCH; ++c) {
    size_t cb = (size_t)(b * NCH + c);
    size_t hidx = (cb * DS + s) * DI + d;
    hinit[hidx] = h;
    h = fmaf(expf(a * sd[cb * DI + d]), h, hend[hidx]);
  }
}

// ---------------- scan pass3: replay with h_init, fuse epilogue ----------------
// y = (scan_y + xh*D) * silu(z), written in place over xh
__global__ __launch_bounds__(256) void k_scan3(const float* __restrict__ delta,
                                               float* __restrict__ xh,  // in-out
                                               const float* __restrict__ xdb,
                                               const float* __restrict__ xz,
                                               const float* __restrict__ A_log,
                                               const float* __restrict__ hinit,
                                               const float* __restrict__ Dp) {
  int tid = threadIdx.x;
  int bid = blockIdx.x;
  int dblk = bid % (DI / 256);
  int c = (bid / (DI / 256)) % NCH;
  int b = bid / ((DI / 256) * NCH);
  int d = dblk * 256 + tid;

  float a[DS];
#pragma unroll
  for (int s = 0; s < DS; ++s) a[s] = -expf(A_log[d * DS + s]);
  float h[DS];
  size_t hbase = (size_t)(b * NCH + c) * DS * DI;
#pragma unroll
  for (int s = 0; s < DS; ++s) h[s] = hinit[hbase + (size_t)s * DI + d];
  float dpar = Dp[d];

  int l0 = c * LCH;
  for (int i = 0; i < LCH; ++i) {
    size_t bl = (size_t)b * L_ + (l0 + i);
    float dt = delta[bl * DI + d];
    float xv = xh[bl * DI + d];
    float u = dt * xv;
    const float* row = xdb + bl * NXP;
    float y = 0.f;
#pragma unroll
    for (int s = 0; s < DS; ++s) {
      float dA = expf(dt * a[s]);
      h[s] = fmaf(dA, h[s], u * row[DTR + s]);       // Bs
      y = fmaf(h[s], row[DTR + DS + s], y);          // Cs
    }
    float z = xz[bl * E2 + DI + d];
    float sig = 1.f / (1.f + expf(-z));
    xh[bl * DI + d] = (y + xv * dpar) * (z * sig);
  }
}

extern "C" void kernel_launch(void* const* d_in, const int* in_sizes, int n_in,
                              void* d_out, int out_size, void* d_ws, size_t ws_size,
                              hipStream_t stream) {
  const float* x      = (const float*)d_in[0];
  const float* W_in   = (const float*)d_in[1];
  const float* conv_w = (const float*)d_in[2];
  const float* conv_b = (const float*)d_in[3];
  const float* W_xproj= (const float*)d_in[4];
  const float* W_dt   = (const float*)d_in[5];
  const float* b_dt   = (const float*)d_in[6];
  const float* A_log  = (const float*)d_in[7];
  const float* D_param= (const float*)d_in[8];
  const float* W_out  = (const float*)d_in[9];
  float* out = (float*)d_out;
  float* ws = (float*)d_ws;

  // workspace layout (floats)
  float* XC    = ws;                  // 4096*768      = 3,145,728
  float* XZ    = XC    + 3145728;     // 4096*3072     = 12,582,912
  float* XH    = XZ    + 12582912;    // 4096*1536     = 6,291,456 (conv out, later y in-place)
  float* XDB   = XH    + 6291456;     // 4096*80       = 327,680
  float* DELTA = XDB   + 327680;      // 4096*1536     = 6,291,456
  float* SD    = DELTA + 6291456;     // 2*128*1536    = 393,216
  float* HEND  = SD    + 393216;      // 2*128*16*1536 = 6,291,456
  float* HINIT = HEND  + 6291456;     // 6,291,456     (total ~166 MB)

  // 1) xc = mean(x, HW)
  k_reduce<<<(B_*L_*C_*16)/256, 256, 0, stream>>>((const float4*)x, XC);
  // 2) xz = xc @ W_in^T   (4096 x 3072, K=768)
  k_gemm<128,128,8,8,0><<<dim3(ML/128, E2/128), 256, 0, stream>>>(
      XC, C_, W_in, C_, XZ, E2, ML, E2, C_, nullptr);
  // 3) xh = silu(causal_conv(xz[:, :DI]))
  k_conv<<<(B_*L_*DI)/256, 256, 0, stream>>>(XZ, conv_w, conv_b, XH);
  // 4) xdb = xh @ W_xproj^T  (4096 x 80, K=1536)
  k_gemm<64,64,4,4,0><<<dim3(ML/64, 2), 256, 0, stream>>>(
      XH, DI, W_xproj, DI, XDB, NXP, ML, NXP, DI, nullptr);
  // 5) delta = softplus(xdb[:, :48] @ W_dt^T + b_dt)  (4096 x 1536, K=48)
  k_gemm<64,64,4,4,1><<<dim3(ML/64, DI/64), 256, 0, stream>>>(
      XDB, NXP, W_dt, DTR, DELTA, DI, ML, DI, DTR, b_dt);
  // 6-8) chunked selective scan + fused output gating (y written over XH)
  k_scan1<<<B_*NCH*(DI/256), 256, 0, stream>>>(DELTA, XH, XDB, A_log, HEND, SD);
  k_scan2<<<(B_*DS*DI)/256, 256, 0, stream>>>(A_log, SD, HEND, HINIT);
  k_scan3<<<B_*NCH*(DI/256), 256, 0, stream>>>(DELTA, XH, XDB, XZ, A_log, HINIT, D_param);
  // 9) out = y @ W_out^T  (4096 x 768, K=1536)
  k_gemm<64,128,4,8,0><<<dim3(ML/64, C_/128), 256, 0, stream>>>(
      XH, DI, W_out, DI, out, C_, ML, C_, DI, nullptr);
}